// Round 10
// baseline (590.352 us; speedup 1.0000x reference)
//
#include <hip/hip_runtime.h>
#include <math.h>

#define B_   8
#define C_   96
#define C2_  192
#define N_   3136        // 56*56
#define R_   25088       // B_*N_
#define OUP_ 192
#define HO_  28
#define NO_  784         // 28*28
#define EPS_ 1e-5f
#define QS2  128         // fspH point stride in u16 (256 B = 16 uint4); ch 96/97 = split(-sq/2)
#define CAP3 64          // per-row candidate pool cap

typedef short bf16x8 __attribute__((ext_vector_type(8)));
typedef float f32x4  __attribute__((ext_vector_type(4)));

// uint4-slot XOR swizzle within a 64-row x 16-col chunk tile (T2): col ^= row&7
__device__ __forceinline__ int swz16(int i) { return (i & ~15) | ((i & 15) ^ ((i >> 4) & 7)); }

// ---------------- fc1 (fp64 accumulate): yd[b,d,n] = sum_c x[b,c,n]*W1[c,d] + b1[d] ----------------
__global__ __launch_bounds__(512) void k_fc1_d(const float* __restrict__ x,
                                               const float* __restrict__ W1,
                                               const float* __restrict__ b1,
                                               double* __restrict__ yd) {
    __shared__ double Wl[96 * 48];
    int tid = threadIdx.x;
    int rl = tid & 255, h = tid >> 8;
    int dbase = blockIdx.y * 48;
    for (int q = tid; q < 96 * 48; q += 512) {
        int c = q / 48, dd = q % 48;
        Wl[c * 48 + dd] = (double)W1[c * 96 + dbase + dd];
    }
    __syncthreads();
    int r = blockIdx.x * 256 + rl;
    int b = r / N_;
    int n = r - b * N_;
    double acc[24];
#pragma unroll
    for (int i = 0; i < 24; i++) acc[i] = 0.0;
    const float* xp = x + (size_t)b * C_ * N_ + n;
    for (int c = 0; c < 96; ++c) {
        double xv = (double)xp[(size_t)c * N_];
        const double* w = &Wl[c * 48 + h * 24];
#pragma unroll
        for (int i = 0; i < 24; ++i) acc[i] += xv * w[i];
    }
    int d0 = dbase + h * 24;
#pragma unroll
    for (int i = 0; i < 24; i++) {
        int d = d0 + i;
        yd[((size_t)b * C_ + d) * N_ + n] = acc[i] + (double)b1[d];
    }
}

// ---------------- fp64 per-channel stats over yd ----------------
__global__ __launch_bounds__(256) void k_stats_chan_d(const double* __restrict__ src,
                                                      double* __restrict__ partial) {
    int c = blockIdx.x;
    int chunk = blockIdx.y;
    const int SPLIT = 16;
    double s = 0.0, ss = 0.0;
    for (int j = chunk * 256 + threadIdx.x; j < R_; j += SPLIT * 256) {
        int b = j / N_, n = j - b * N_;
        double v = src[((size_t)b * C_ + c) * N_ + n];
        s += v;
        ss += v * v;
    }
    __shared__ double red[8];
    for (int off = 32; off; off >>= 1) {
        s += __shfl_down(s, off, 64);
        ss += __shfl_down(ss, off, 64);
    }
    int lane = threadIdx.x & 63, w = threadIdx.x >> 6;
    if (lane == 0) { red[w * 2] = s; red[w * 2 + 1] = ss; }
    __syncthreads();
    if (threadIdx.x == 0) {
        s = red[0] + red[2] + red[4] + red[6];
        ss = red[1] + red[3] + red[5] + red[7];
        partial[(c * SPLIT + chunk) * 2] = s;
        partial[(c * SPLIT + chunk) * 2 + 1] = ss;
    }
}

__global__ void k_stats_reduce_d(const double* __restrict__ partial, double* __restrict__ stats) {
    int c = blockIdx.x * blockDim.x + threadIdx.x;
    if (c >= 96) return;
    double s = 0.0, ss = 0.0;
    for (int k = 0; k < 16; k++) {
        s += partial[(c * 16 + k) * 2];
        ss += partial[(c * 16 + k) * 2 + 1];
    }
    double m = s / (double)R_;
    double var = ss / (double)R_ - m * m;
    stats[c * 2] = m;
    stats[c * 2 + 1] = 1.0 / sqrt(var + 1e-5);
}

// ---------------- fp32 per-channel stats ----------------
__global__ __launch_bounds__(256) void k_stats_chan(const float* __restrict__ src,
                                                    float* __restrict__ partial,
                                                    int Cn, int Nsp, int total) {
    int c = blockIdx.x;
    int chunk = blockIdx.y;
    int SPLIT = gridDim.y;
    float s = 0.f, ss = 0.f;
    for (int j = chunk * 256 + threadIdx.x; j < total; j += SPLIT * 256) {
        int b = j / Nsp, n = j - b * Nsp;
        float v = src[((size_t)b * Cn + c) * Nsp + n];
        s += v;
        ss += v * v;
    }
    __shared__ float red[8];
    for (int off = 32; off; off >>= 1) {
        s += __shfl_down(s, off, 64);
        ss += __shfl_down(ss, off, 64);
    }
    int lane = threadIdx.x & 63, w = threadIdx.x >> 6;
    if (lane == 0) { red[w * 2] = s; red[w * 2 + 1] = ss; }
    __syncthreads();
    if (threadIdx.x == 0) {
        s = red[0] + red[2] + red[4] + red[6];
        ss = red[1] + red[3] + red[5] + red[7];
        partial[(c * SPLIT + chunk) * 2] = s;
        partial[(c * SPLIT + chunk) * 2 + 1] = ss;
    }
}

__global__ void k_stats_reduce(const float* __restrict__ partial, float* __restrict__ stats,
                               int Cn, int SPLIT, float invcount) {
    int c = blockIdx.x * blockDim.x + threadIdx.x;
    if (c >= Cn) return;
    float s = 0.f, ss = 0.f;
    for (int k = 0; k < SPLIT; k++) {
        s += partial[(c * SPLIT + k) * 2];
        ss += partial[(c * SPLIT + k) * 2 + 1];
    }
    float m = s * invcount;
    float var = ss * invcount - m * m;
    stats[c * 2] = m;
    stats[c * 2 + 1] = 1.0f / sqrtf(var + EPS_);
}

// parallel reduce for k_bne_stats partials: one block per channel
__global__ __launch_bounds__(256) void k_stats_reduce_b2(const float* __restrict__ partial,
                                                         float* __restrict__ stats,
                                                         float invcount) {
    int c = blockIdx.x;      // 0..191
    float s = 0.f, ss = 0.f;
    for (int k = threadIdx.x; k < 784; k += 256) {
        s  += partial[(size_t)k * 384 + c];
        ss += partial[(size_t)k * 384 + 192 + c];
    }
    __shared__ float red[8];
    for (int off = 32; off; off >>= 1) {
        s += __shfl_down(s, off, 64);
        ss += __shfl_down(ss, off, 64);
    }
    int lane = threadIdx.x & 63, w = threadIdx.x >> 6;
    if (lane == 0) { red[w * 2] = s; red[w * 2 + 1] = ss; }
    __syncthreads();
    if (threadIdx.x == 0) {
        s = red[0] + red[2] + red[4] + red[6];
        ss = red[1] + red[3] + red[5] + red[7];
        float m = s * invcount;
        float var = ss * invcount - m * m;
        stats[c * 2] = m;
        stats[c * 2 + 1] = 1.0f / sqrtf(var + EPS_);
    }
}

// ---------------- BN1 apply + LDS transpose: ftc (c-major f32), ftp64 (row-major), fspH
// (bf16-hi + norm channels 96/97, zeros 98-127), sq64 — all coalesced ----------------
__global__ __launch_bounds__(256) void k_bn1_tr(const double* __restrict__ yd,
                                                const double* __restrict__ stats,
                                                const float* __restrict__ g,
                                                const float* __restrict__ be,
                                                float* __restrict__ ftc,
                                                double* __restrict__ ftp64,
                                                unsigned short* __restrict__ fspH,
                                                double* __restrict__ sq64) {
    __shared__ double tile[64 * 97];     // [point][chan], stride 97
    __shared__ double dsq[64][4];
    int b = blockIdx.y;
    int n0 = blockIdx.x * 64;
    int tid = threadIdx.x;
    int n = tid & 63, w = tid >> 6;
    for (int k = 0; k < 24; ++k) {
        int c = k * 4 + w;
        size_t gi = ((size_t)b * C_ + c) * N_ + n0 + n;
        double m = stats[c * 2], rs = stats[c * 2 + 1];
        double v = (double)g[c] * (yd[gi] - m) * rs + (double)be[c];
        ftc[gi] = (float)v;
        tile[n * 97 + c] = v;
    }
    __syncthreads();
    int p = n, q = w;
    double vals[24];
    double s = 0.0;
    const double* lp = &tile[p * 97 + q * 24];
#pragma unroll
    for (int m2 = 0; m2 < 24; ++m2) { vals[m2] = lp[m2]; s += vals[m2] * vals[m2]; }
    dsq[p][q] = s;
    double* dst = ftp64 + ((size_t)b * N_ + n0 + p) * C_ + q * 24;
#pragma unroll
    for (int m2 = 0; m2 < 24; m2 += 2) *(double2*)&dst[m2] = make_double2(vals[m2], vals[m2 + 1]);
    unsigned* hdst = (unsigned*)(fspH + ((size_t)b * N_ + n0 + p) * QS2);
#pragma unroll
    for (int m2 = 0; m2 < 24; m2 += 2) {
        unsigned u0 = __float_as_uint((float)vals[m2]);
        unsigned u1 = __float_as_uint((float)vals[m2 + 1]);
        unsigned h0 = (u0 + 0x7fffu + ((u0 >> 16) & 1u)) >> 16;      // RNE to bf16
        unsigned h1 = (u1 + 0x7fffu + ((u1 >> 16) & 1u)) >> 16;
        hdst[q * 12 + (m2 >> 1)] = h0 | (h1 << 16);
    }
    __syncthreads();
    if (tid < 64) {
        double tot = dsq[tid][0] + dsq[tid][1] + dsq[tid][2] + dsq[tid][3];
        sq64[(size_t)b * N_ + n0 + tid] = tot;
        // channels 96/97 = split-bf16(-tot/2); 98..127 = 0 (norm folded into MFMA K-slice 3)
        float t32 = (float)(-0.5 * tot);
        unsigned u0 = __float_as_uint(t32);
        unsigned h0 = (u0 + 0x7fffu + ((u0 >> 16) & 1u)) >> 16;
        float resid = t32 - __uint_as_float(h0 << 16);
        unsigned u1 = __float_as_uint(resid);
        unsigned h1 = (u1 + 0x7fffu + ((u1 >> 16) & 1u)) >> 16;
        unsigned* hd = (unsigned*)(fspH + ((size_t)b * N_ + n0 + tid) * QS2);
        hd[48] = h0 | (h1 << 16);
#pragma unroll
        for (int k2 = 49; k2 < 64; ++k2) hd[k2] = 0u;
    }
}

// ---------------- pass 0: per-query chunk minima (d = -2*acc, norm folded in) ----------------
// grid (49 qblocks, 2 cand-halves, 8 b); 4 waves; wave w = 16 queries x all 64 cands/chunk
__global__ __launch_bounds__(256) void k_dist_min(const unsigned short* __restrict__ fspH,
                                                  unsigned short* __restrict__ cminG) {
    __shared__ __align__(16) char lds[32768];    // buf0 | buf1 (16KB each)
    int b = blockIdx.z, half = blockIdx.y;
    int q0 = blockIdx.x * 64;
    int tid = threadIdx.x, w = tid >> 6, l = tid & 63;
    int ch0 = half * 25;
    int nch = half ? 24 : 25;
    const int koff = (l >> 4) * 8;

    {   // queries -> buf1, first chunk -> buf0 (both swizzled)
        const uint4* qsrc = (const uint4*)(fspH + ((size_t)b * N_ + q0) * QS2);
        const uint4* csrc = (const uint4*)(fspH + ((size_t)b * N_ + ch0 * 64) * QS2);
        uint4* qb = (uint4*)(lds + 16384);
        uint4* cb = (uint4*)lds;
        for (int i = tid; i < 1024; i += 256) { qb[swz16(i)] = qsrc[i]; cb[swz16(i)] = csrc[i]; }
    }
    __syncthreads();
    bf16x8 Bq[4];
    {
        const unsigned short* Ql = (const unsigned short*)(lds + 16384);
        int qr = w * 16 + (l & 15);
#pragma unroll
        for (int s = 0; s < 3; ++s) {
            int col = (s * 4 + (l >> 4)) ^ (qr & 7);
            Bq[s] = *(const bf16x8*)&Ql[qr * QS2 + col * 8];
        }
        bf16x8 z = {0, 0, 0, 0, 0, 0, 0, 0};
        if ((l >> 4) == 0) { z[0] = (short)0x3F80; z[1] = (short)0x3F80; }   // bf16 1.0
        Bq[3] = z;
    }
    __syncthreads();   // buf1 free

    int cur = 0;
    for (int t = 0; t < nch; ++t) {
        int chg = ch0 + t;
        bool pf = (t < nch - 1);
        uint4 st0, st1, st2, st3;
        if (pf) {
            const uint4* src = (const uint4*)(fspH + ((size_t)b * N_ + (chg + 1) * 64) * QS2);
            st0 = src[tid]; st1 = src[tid + 256]; st2 = src[tid + 512]; st3 = src[tid + 768];
        }
        const unsigned short* Bc = (const unsigned short*)(lds + cur * 16384);
        f32x4 acc[4];
#pragma unroll
        for (int ct = 0; ct < 4; ++ct) acc[ct] = (f32x4){0.f, 0.f, 0.f, 0.f};
#pragma unroll
        for (int s = 0; s < 4; ++s) {
#pragma unroll
            for (int ct = 0; ct < 4; ++ct) {
                int cr = ct * 16 + (l & 15);
                int col = (s * 4 + (l >> 4)) ^ (cr & 7);
                bf16x8 Ac = *(const bf16x8*)&Bc[cr * QS2 + col * 8];
                acc[ct] = __builtin_amdgcn_mfma_f32_16x16x32_bf16(Ac, Bq[s], acc[ct], 0, 0, 0);
            }
        }
        float mx = -1e30f;
#pragma unroll
        for (int ct = 0; ct < 4; ++ct)
#pragma unroll
            for (int j = 0; j < 4; ++j) mx = fmaxf(mx, acc[ct][j]);
        mx = fmaxf(mx, __shfl_xor(mx, 16, 64));
        mx = fmaxf(mx, __shfl_xor(mx, 32, 64));
        if (l < 16) {
            float dmin = -2.f * mx;
            unsigned u = __float_as_uint(dmin);
            unsigned ku = u ^ (0x80000000u | (unsigned)((int)u >> 31));   // monotone key
            cminG[((size_t)(b * N_ + q0 + w * 16 + l)) * 49 + chg] = (unsigned short)(ku >> 16);
        }
        if (pf) {
            uint4* dst = (uint4*)(lds + (cur ^ 1) * 16384);
            dst[swz16(tid)] = st0;
            dst[swz16(tid + 256)] = st1;
            dst[swz16(tid + 512)] = st2;
            dst[swz16(tid + 768)] = st3;
        }
        __syncthreads();
        cur ^= 1;
    }
}

// ---------------- t9 threshold per query (9th smallest chunk-min) + poolCnt zero ----------------
__global__ __launch_bounds__(256) void k_t9(const unsigned short* __restrict__ cminG,
                                            float* __restrict__ thr2f,
                                            unsigned* __restrict__ poolCnt) {
    int q = blockIdx.x * 256 + threadIdx.x;
    if (q >= R_) return;
    const unsigned short* p = cminG + (size_t)q * 49;
    unsigned short top[9];
#pragma unroll
    for (int j = 0; j < 9; ++j) top[j] = 0xFFFFu;
    for (int i = 0; i < 49; ++i) {
        unsigned short v = p[i];
        if (v < top[8]) {
            top[8] = v;
#pragma unroll
            for (int j = 8; j >= 1; --j)
                if (top[j] < top[j - 1]) { unsigned short tt = top[j]; top[j] = top[j - 1]; top[j - 1] = tt; }
        }
    }
    unsigned ku = ((unsigned)top[8] << 16) | 0xFFFFu;    // bucket upper bound
    float f = (ku & 0x80000000u) ? __uint_as_float(ku ^ 0x80000000u) : __uint_as_float(~ku);
    float t9 = f + fabsf(f) * 0.008f + 0.75f;            // 2e margin for hi-bf16 dot + norm split
    thr2f[q] = -0.5f * t9;                               // acc-space: d<=t9  <=>  acc >= -t9/2
    poolCnt[q] = 0u;
}

// ---------------- pass 1: compaction (global atomics; order-independent downstream) ----------------
__global__ __launch_bounds__(256) void k_dist_cmp(const unsigned short* __restrict__ fspH,
                                                  const float* __restrict__ thr2f,
                                                  unsigned short* __restrict__ poolC,
                                                  unsigned* __restrict__ poolCnt) {
    __shared__ __align__(16) char lds[32768];
    int b = blockIdx.z, half = blockIdx.y;
    int q0 = blockIdx.x * 64;
    int tid = threadIdx.x, w = tid >> 6, l = tid & 63;
    int ch0 = half * 25;
    int nch = half ? 24 : 25;
    const int koff = (l >> 4) * 8;
    int qg = b * N_ + q0 + w * 16 + (l & 15);   // this lane's query (global row)
    float thr2r = thr2f[qg];

    {
        const uint4* qsrc = (const uint4*)(fspH + ((size_t)b * N_ + q0) * QS2);
        const uint4* csrc = (const uint4*)(fspH + ((size_t)b * N_ + ch0 * 64) * QS2);
        uint4* qb = (uint4*)(lds + 16384);
        uint4* cb = (uint4*)lds;
        for (int i = tid; i < 1024; i += 256) { qb[swz16(i)] = qsrc[i]; cb[swz16(i)] = csrc[i]; }
    }
    __syncthreads();
    bf16x8 Bq[4];
    {
        const unsigned short* Ql = (const unsigned short*)(lds + 16384);
        int qr = w * 16 + (l & 15);
#pragma unroll
        for (int s = 0; s < 3; ++s) {
            int col = (s * 4 + (l >> 4)) ^ (qr & 7);
            Bq[s] = *(const bf16x8*)&Ql[qr * QS2 + col * 8];
        }
        bf16x8 z = {0, 0, 0, 0, 0, 0, 0, 0};
        if ((l >> 4) == 0) { z[0] = (short)0x3F80; z[1] = (short)0x3F80; }
        Bq[3] = z;
    }
    __syncthreads();

    int cur = 0;
    for (int t = 0; t < nch; ++t) {
        int chg = ch0 + t;
        int c0 = chg * 64;
        bool pf = (t < nch - 1);
        uint4 st0, st1, st2, st3;
        if (pf) {
            const uint4* src = (const uint4*)(fspH + ((size_t)b * N_ + (chg + 1) * 64) * QS2);
            st0 = src[tid]; st1 = src[tid + 256]; st2 = src[tid + 512]; st3 = src[tid + 768];
        }
        const unsigned short* Bc = (const unsigned short*)(lds + cur * 16384);
        f32x4 acc[4];
#pragma unroll
        for (int ct = 0; ct < 4; ++ct) acc[ct] = (f32x4){0.f, 0.f, 0.f, 0.f};
#pragma unroll
        for (int s = 0; s < 4; ++s) {
#pragma unroll
            for (int ct = 0; ct < 4; ++ct) {
                int cr = ct * 16 + (l & 15);
                int col = (s * 4 + (l >> 4)) ^ (cr & 7);
                bf16x8 Ac = *(const bf16x8*)&Bc[cr * QS2 + col * 8];
                acc[ct] = __builtin_amdgcn_mfma_f32_16x16x32_bf16(Ac, Bq[s], acc[ct], 0, 0, 0);
            }
        }
#pragma unroll
        for (int ct = 0; ct < 4; ++ct)
#pragma unroll
            for (int j = 0; j < 4; ++j) {
                if (acc[ct][j] >= thr2r) {                       // rare
                    unsigned pos = atomicAdd(&poolCnt[qg], 1u);
                    if (pos < (unsigned)CAP3)
                        poolC[(size_t)qg * CAP3 + pos] = (unsigned short)(c0 + ct * 16 + (l >> 4) * 4 + j);
                }
            }
        if (pf) {
            uint4* dst = (uint4*)(lds + (cur ^ 1) * 16384);
            dst[swz16(tid)] = st0;
            dst[swz16(tid + 256)] = st1;
            dst[swz16(tid + 512)] = st2;
            dst[swz16(tid + 768)] = st3;
        }
        __syncthreads();
        cur ^= 1;
    }
}

// ---------------- fp64 exact re-rank of variable pool -> top-9 set ----------------
__global__ __launch_bounds__(256) void k_rerank_d(const unsigned short* __restrict__ poolC,
                                                  const unsigned* __restrict__ poolCnt,
                                                  const double* __restrict__ ftp64,
                                                  const double* __restrict__ sq64,
                                                  int* __restrict__ idx) {
    int tid = threadIdx.x;
    int wv = tid >> 6, l = tid & 63;
    int rr = blockIdx.x * 4 + wv;
    int b = rr / N_;
    int cnt = (int)poolCnt[rr];
    if (cnt > CAP3) cnt = CAP3;
    int e = l & 3;
    double qreg[24];
    {
        const double* qb = ftp64 + (size_t)rr * C_ + e * 24;
#pragma unroll
        for (int m = 0; m < 24; ++m) qreg[m] = qb[m];
    }
    double dv[4];
    int jv[4];
#pragma unroll
    for (int gG = 0; gG < 4; ++gG) { dv[gG] = 1e300; jv[gG] = 0x7fffffff; }
#pragma unroll
    for (int gG = 0; gG < 4; ++gG) {
        if (gG * 16 >= cnt) break;                 // wave-uniform skip
        int ci = gG * 16 + (l >> 2);
        bool valid = ci < cnt;
        int j = valid ? (int)poolC[(size_t)rr * CAP3 + ci] : 0;
        const double* cb = ftp64 + ((size_t)b * N_ + j) * C_ + e * 24;
        double p = 0.0;
#pragma unroll
        for (int m = 0; m < 24; ++m) p += qreg[m] * cb[m];
        p += __shfl_xor(p, 1, 64);
        p += __shfl_xor(p, 2, 64);
        if (valid) {
            dv[gG] = sq64[(size_t)b * N_ + j] - 2.0 * p;
            jv[gG] = j;
        }
    }
#pragma unroll
    for (int r = 0; r < 9; ++r) {
        double dm = dv[0]; int jm = jv[0];
#pragma unroll
        for (int gG = 1; gG < 4; ++gG)
            if (dv[gG] < dm || (dv[gG] == dm && jv[gG] < jm)) { dm = dv[gG]; jm = jv[gG]; }
#pragma unroll
        for (int off = 1; off <= 32; off <<= 1) {
            double od = __shfl_xor(dm, off, 64);
            int oj = __shfl_xor(jm, off, 64);
            if (od < dm || (od == dm && oj < jm)) { dm = od; jm = oj; }
        }
        if (l == 0) idx[(size_t)rr * 9 + r] = jm;
#pragma unroll
        for (int gG = 0; gG < 4; ++gG)
            if (jv[gG] == jm) dv[gG] = 1e300;
    }
}

// ---------------- fused: u = ft·(Wtop-Wbot)+b_edge AND v = ft·Wbot ----------------
__global__ __launch_bounds__(512) void k_gemm_uv2(const float* __restrict__ ftc,
                                                  const float* __restrict__ We,
                                                  const float* __restrict__ beb,
                                                  float* __restrict__ u,
                                                  float* __restrict__ v) {
    __shared__ float Wl[2][96 * 48];
    int tid = threadIdx.x;
    int rl = tid & 255, h = tid >> 8;
    int dbase = blockIdx.y * 48;
    for (int q = tid; q < 96 * 48; q += 512) {
        int c = q / 48, dd = q % 48;
        float wb = We[(96 + c) * C2_ + dbase + dd];
        Wl[1][q] = wb;
        Wl[0][q] = We[c * C2_ + dbase + dd] - wb;
    }
    __syncthreads();
    int r = blockIdx.x * 256 + rl;
    int b = r / N_, n = r - b * N_;
    float a0[24], a1[24];
#pragma unroll
    for (int i = 0; i < 24; i++) { a0[i] = 0.f; a1[i] = 0.f; }
    const float* xp = ftc + (size_t)b * C_ * N_ + n;
    for (int c = 0; c < 96; ++c) {
        float xv = xp[(size_t)c * N_];
        const float4* w40 = (const float4*)&Wl[0][c * 48 + h * 24];
        const float4* w41 = (const float4*)&Wl[1][c * 48 + h * 24];
#pragma unroll
        for (int i = 0; i < 6; ++i) {
            float4 w0 = w40[i], w1 = w41[i];
            a0[i * 4 + 0] += xv * w0.x; a0[i * 4 + 1] += xv * w0.y;
            a0[i * 4 + 2] += xv * w0.z; a0[i * 4 + 3] += xv * w0.w;
            a1[i * 4 + 0] += xv * w1.x; a1[i * 4 + 1] += xv * w1.y;
            a1[i * 4 + 2] += xv * w1.z; a1[i * 4 + 3] += xv * w1.w;
        }
    }
    int d0 = dbase + h * 24;
    float* up = u + (size_t)r * C2_ + d0;
    float* vp = v + (size_t)r * C2_ + d0;
#pragma unroll
    for (int i = 0; i < 6; ++i) {
        float4 ou, ov;
        ou.x = a0[i * 4 + 0] + beb[d0 + i * 4 + 0];
        ou.y = a0[i * 4 + 1] + beb[d0 + i * 4 + 1];
        ou.z = a0[i * 4 + 2] + beb[d0 + i * 4 + 2];
        ou.w = a0[i * 4 + 3] + beb[d0 + i * 4 + 3];
        ov.x = a1[i * 4 + 0]; ov.y = a1[i * 4 + 1];
        ov.z = a1[i * 4 + 2]; ov.w = a1[i * 4 + 3];
        ((float4*)up)[i] = ou;
        ((float4*)vp)[i] = ov;
    }
}

// ---------------- edge-BN stats: e = u[n,d] + v[j,d] over all (row,k) ----------------
__global__ __launch_bounds__(192) void k_bne_stats(const float* __restrict__ u,
                                                   const float* __restrict__ v,
                                                   const int* __restrict__ idx,
                                                   float* __restrict__ partial) {
    int d = threadIdx.x;
    int row0 = blockIdx.x * 32;
    int b = row0 / N_;
    float s = 0.f, ss = 0.f;
    for (int r = 0; r < 32; ++r) {
        int row = row0 + r;
        float ud = u[(size_t)row * C2_ + d];
        const int* ip = idx + (size_t)row * 9;
#pragma unroll
        for (int k = 0; k < 9; k++) {
            int j = ip[k];
            float e = ud + v[((size_t)b * N_ + j) * C2_ + d];
            s += e;
            ss += e * e;
        }
    }
    partial[(size_t)blockIdx.x * 384 + d] = s;
    partial[(size_t)blockIdx.x * 384 + 192 + d] = ss;
}

// ---------------- edge BN+relu+max over k, then fc2 (192->96) ----------------
__global__ __launch_bounds__(192) void k_edge_fc2(const float* __restrict__ u,
                                                  const float* __restrict__ v,
                                                  const int* __restrict__ idx,
                                                  const float* __restrict__ statsE,
                                                  const float* __restrict__ ge,
                                                  const float* __restrict__ bee,
                                                  const float* __restrict__ W2,
                                                  const float* __restrict__ b2,
                                                  float* __restrict__ out2) {
    __shared__ float gl[16][C2_];
    __shared__ float g2[C_][16];
    int tid = threadIdx.x;
    int row0 = blockIdx.x * 16;
    int b = row0 / N_;
    int n0 = row0 - b * N_;
    {
        int d = tid;
        float m = statsE[d * 2], rs = statsE[d * 2 + 1];
        float ga = ge[d], bb = bee[d];
        for (int r = 0; r < 16; ++r) {
            int row = row0 + r;
            float ud = u[(size_t)row * C2_ + d];
            const int* ip = idx + (size_t)row * 9;
            float gm = 0.f;                      // relu-then-max == max with 0
#pragma unroll
            for (int k = 0; k < 9; k++) {
                int j = ip[k];
                float e = ud + v[((size_t)b * N_ + j) * C2_ + d];
                float val = ga * (e - m) * rs + bb;
                gm = fmaxf(gm, val);
            }
            gl[r][d] = gm;
        }
    }
    __syncthreads();
    {
        int rr = tid / 24;
        int dq = tid % 24;
        for (int rep = 0; rep < 2; ++rep) {
            int r = rr + rep * 8;
            float4 acc = *(const float4*)&b2[dq * 4];
            for (int d = 0; d < C2_; ++d) {
                float gv = gl[r][d];
                float4 w = *(const float4*)&W2[d * C_ + dq * 4];
                acc.x += gv * w.x;
                acc.y += gv * w.y;
                acc.z += gv * w.z;
                acc.w += gv * w.w;
            }
            g2[dq * 4 + 0][r] = acc.x;
            g2[dq * 4 + 1][r] = acc.y;
            g2[dq * 4 + 2][r] = acc.z;
            g2[dq * 4 + 3][r] = acc.w;
        }
    }
    __syncthreads();
    for (int q = tid; q < 96 * 4; q += 192) {
        int dd = q / 4, part = q % 4;
        float4 val = *(const float4*)&g2[dd][part * 4];
        *(float4*)&out2[((size_t)b * C_ + dd) * N_ + n0 + part * 4] = val;
    }
}

// ---------------- t = bn2(out2) + x, with fused per-channel stats of t ----------------
__global__ __launch_bounds__(256) void k_bn2_add_st(const float* __restrict__ out2,
                                                    const float* __restrict__ x,
                                                    const float* __restrict__ stats,
                                                    const float* __restrict__ g,
                                                    const float* __restrict__ be,
                                                    float* __restrict__ t,
                                                    float* __restrict__ partial) {
    int c = blockIdx.x;
    int chunk = blockIdx.y;
    const int SPLIT = 16;
    float m = stats[c * 2], rs = stats[c * 2 + 1];
    float ga = g[c], bb = be[c];
    float s = 0.f, ss = 0.f;
    for (int j = chunk * 256 + threadIdx.x; j < R_; j += SPLIT * 256) {
        int b = j / N_, n = j - b * N_;
        size_t i = ((size_t)b * C_ + c) * N_ + n;
        float tv = ga * (out2[i] - m) * rs + bb + x[i];
        t[i] = tv;
        s += tv;
        ss += tv * tv;
    }
    __shared__ float red[8];
    for (int off = 32; off; off >>= 1) {
        s += __shfl_down(s, off, 64);
        ss += __shfl_down(ss, off, 64);
    }
    int lane = threadIdx.x & 63, w = threadIdx.x >> 6;
    if (lane == 0) { red[w * 2] = s; red[w * 2 + 1] = ss; }
    __syncthreads();
    if (threadIdx.x == 0) {
        s = red[0] + red[2] + red[4] + red[6];
        ss = red[1] + red[3] + red[5] + red[7];
        partial[(c * SPLIT + chunk) * 2] = s;
        partial[(c * SPLIT + chunk) * 2 + 1] = ss;
    }
}

// ---------------- s = relu(sabn(t)) ----------------
__global__ __launch_bounds__(256) void k_sabn_relu(const float* __restrict__ t,
                                                   const float* __restrict__ stats,
                                                   const float* __restrict__ g,
                                                   const float* __restrict__ be,
                                                   float* __restrict__ s) {
    int i = blockIdx.x * 256 + threadIdx.x;
    if (i >= B_ * C_ * N_) return;
    int c = (i / N_) % C_;
    s[i] = fmaxf(g[c] * (t[i] - stats[c * 2]) * stats[c * 2 + 1] + be[c], 0.f);
}

// ---------------- conv 3x3 stride 2 pad 1, 96->192 ----------------
__global__ __launch_bounds__(256) void k_conv(const float* __restrict__ s,
                                              const float* __restrict__ Wd,
                                              const float* __restrict__ bd,
                                              float* __restrict__ z) {
    __shared__ float Wl[96 * 9 * 16];
    int b = blockIdx.z;
    int oc0 = blockIdx.y * 16;
    int p = blockIdx.x * 256 + threadIdx.x;
    for (int i = threadIdx.x; i < 96 * 9 * 16; i += 256) {
        int oc = i & 15;
        int icq = i >> 4;
        Wl[i] = Wd[(size_t)(oc0 + oc) * 864 + icq];
    }
    __syncthreads();
    if (p >= NO_) return;
    int oh = p / HO_, ow = p % HO_;
    float acc[16];
#pragma unroll
    for (int i = 0; i < 16; i++) acc[i] = 0.f;
    int ih0 = oh * 2 - 1, iw0 = ow * 2 - 1;
    const float* sb = s + (size_t)b * C_ * N_;
    for (int ic = 0; ic < 96; ++ic) {
        const float* sp = sb + (size_t)ic * N_;
        float in[9];
#pragma unroll
        for (int kh = 0; kh < 3; kh++) {
            int ih = ih0 + kh;
            bool okh = (unsigned)ih < 56u;
#pragma unroll
            for (int kw = 0; kw < 3; kw++) {
                int iw = iw0 + kw;
                bool ok = okh && ((unsigned)iw < 56u);
                in[kh * 3 + kw] = ok ? sp[ih * 56 + iw] : 0.f;
            }
        }
#pragma unroll
        for (int q = 0; q < 9; q++) {
            float iv = in[q];
            const float4* w4 = (const float4*)&Wl[(ic * 9 + q) * 16];
#pragma unroll
            for (int j = 0; j < 4; j++) {
                float4 w = w4[j];
                acc[j * 4 + 0] += iv * w.x;
                acc[j * 4 + 1] += iv * w.y;
                acc[j * 4 + 2] += iv * w.z;
                acc[j * 4 + 3] += iv * w.w;
            }
        }
    }
#pragma unroll
    for (int i = 0; i < 16; i++)
        z[((size_t)b * OUP_ + oc0 + i) * NO_ + p] = acc[i] + bd[oc0 + i];
}

// ---------------- out = relu(dwbn(z)) ----------------
__global__ __launch_bounds__(256) void k_out(const float* __restrict__ z,
                                             const float* __restrict__ stats,
                                             const float* __restrict__ g,
                                             const float* __restrict__ be,
                                             float* __restrict__ out) {
    int i = blockIdx.x * 256 + threadIdx.x;
    if (i >= B_ * OUP_ * NO_) return;
    int c = (i / NO_) % OUP_;
    out[i] = fmaxf(g[c] * (z[i] - stats[c * 2]) * stats[c * 2 + 1] + be[c], 0.f);
}

extern "C" void kernel_launch(void* const* d_in, const int* in_sizes, int n_in,
                              void* d_out, int out_size, void* d_ws, size_t ws_size,
                              hipStream_t stream) {
    const float* x     = (const float*)d_in[0];
    const float* W_fc1 = (const float*)d_in[1];
    const float* b_fc1 = (const float*)d_in[2];
    const float* g_bn1 = (const float*)d_in[3];
    const float* be_bn1= (const float*)d_in[4];
    const float* W_edge= (const float*)d_in[5];
    const float* b_edge= (const float*)d_in[6];
    const float* g_bne = (const float*)d_in[7];
    const float* be_bne= (const float*)d_in[8];
    const float* W_fc2 = (const float*)d_in[9];
    const float* b_fc2 = (const float*)d_in[10];
    const float* g_bn2 = (const float*)d_in[11];
    const float* be_bn2= (const float*)d_in[12];
    const float* g_sabn= (const float*)d_in[13];
    const float* be_sabn=(const float*)d_in[14];
    const float* W_dw  = (const float*)d_in[15];
    const float* b_dw  = (const float*)d_in[16];
    const float* g_dwbn= (const float*)d_in[17];
    const float* be_dwbn=(const float*)d_in[18];

    // byte-offset workspace layout with lifetime-based aliasing (~74.8 MB)
    char* base = (char*)d_ws;
    float*  ftc   = (float*)(base + 0);                    //  9,633,792 [bn1_tr -> gemm]; then sbuf
    float*  sbuf  = (float*)(base + 0);
    double* ftp64 = (double*)(base + 9633792);             // 19,267,584 [bn1_tr -> rerank]; then uu
    float*  uu    = (float*)(base + 9633792);
    double* yd    = (double*)(base + 28901376);            // 19,267,584 [fc1 -> bn1_tr]; then vv
    float*  vv    = (float*)(base + 28901376);
    unsigned short* fspH = (unsigned short*)(base + 48168960); // 6,422,528 [bn1_tr -> dist]; then out2
    float*  out2  = (float*)(base + 48168960);
    unsigned short* poolC = (unsigned short*)(base + 57802752); // 3,211,264 [cmp -> rerank]; then tbuf
    float*  tbuf  = (float*)(base + 57802752);
    double* sq64  = (double*)(base + 67436544);            //    200,704
    int*    idx   = (int*)(base + 67637248);               //    903,168 [rerank -> edge]
    unsigned* poolCnt = (unsigned*)(base + 68540416);      //    100,352
    float*  thr2f = (float*)(base + 68640768);             //    100,352 [t9 -> cmp]
    float*  partial = (float*)(base + 68741120);           //  1,204,224 max
    double* partiald = (double*)(base + 68741120);         //     24,576 (earlier use, same region)
    double* stats1d = (double*)(base + 69945344);          //      1,536
    float*  statsE  = (float*)(base + 69946880);
    float*  stats2  = (float*)(base + 69948416);
    float*  statsS  = (float*)(base + 69949952);
    float*  statsD  = (float*)(base + 69951488);
    float*  zbuf  = (float*)(base + 69953024);             //  4,816,896 [conv -> out]
    unsigned short* cminG = (unsigned short*)(base + 69953024); // 2,458,624 [dist_min -> t9] (aliases zbuf)

    // fc1 + BN1 (fp64 path); bn1_tr fuses apply+transpose+bf16-split+norm-fold+sqrows
    k_fc1_d<<<dim3(98, 2), 512, 0, stream>>>(x, W_fc1, b_fc1, yd);
    k_stats_chan_d<<<dim3(96, 16), 256, 0, stream>>>(yd, partiald);
    k_stats_reduce_d<<<1, 256, 0, stream>>>(partiald, stats1d);
    k_bn1_tr<<<dim3(49, B_), 256, 0, stream>>>(yd, stats1d, g_bn1, be_bn1, ftc, ftp64, fspH, sq64);

    // kNN: MFMA chunk-minima (2x parallel) -> t9 threshold -> compaction (2x parallel) -> fp64 rerank
    k_dist_min<<<dim3(49, 2, B_), 256, 0, stream>>>(fspH, cminG);
    k_t9<<<98, 256, 0, stream>>>(cminG, thr2f, poolCnt);
    k_dist_cmp<<<dim3(49, 2, B_), 256, 0, stream>>>(fspH, thr2f, poolC, poolCnt);
    k_rerank_d<<<6272, 256, 0, stream>>>(poolC, poolCnt, ftp64, sq64, idx);

    // fused edge GEMMs: u = ft·(Wtop-Wbot)+b_edge, v = ft·Wbot (overwrite ftp64/yd)
    k_gemm_uv2<<<dim3(98, 4), 512, 0, stream>>>(ftc, W_edge, b_edge, uu, vv);

    // edge BN stats, then BN+relu+max+fc2
    k_bne_stats<<<784, 192, 0, stream>>>(uu, vv, idx, partial);
    k_stats_reduce_b2<<<192, 256, 0, stream>>>(partial, statsE, 1.0f / 225792.0f);
    k_edge_fc2<<<1568, 192, 0, stream>>>(uu, vv, idx, statsE, g_bne, be_bne, W_fc2, b_fc2, out2);

    // BN2 + shortcut (stats of t fused into the add pass)
    k_stats_chan<<<dim3(96, 16), 256, 0, stream>>>(out2, partial, 96, N_, R_);
    k_stats_reduce<<<1, 256, 0, stream>>>(partial, stats2, 96, 16, 1.0f / (float)R_);
    k_bn2_add_st<<<dim3(96, 16), 256, 0, stream>>>(out2, x, stats2, g_bn2, be_bn2, tbuf, partial);
    k_stats_reduce<<<1, 256, 0, stream>>>(partial, statsS, 96, 16, 1.0f / (float)R_);
    k_sabn_relu<<<9408, 256, 0, stream>>>(tbuf, statsS, g_sabn, be_sabn, sbuf);

    // conv + dwbn + relu
    k_conv<<<dim3(4, 12, 8), 256, 0, stream>>>(sbuf, W_dw, b_dw, zbuf);
    k_stats_chan<<<dim3(192, 8), 256, 0, stream>>>(zbuf, partial, 192, NO_, 6272);
    k_stats_reduce<<<1, 256, 0, stream>>>(partial, statsD, 192, 8, 1.0f / 6272.0f);
    k_out<<<4705, 256, 0, stream>>>(zbuf, statsD, g_dwbn, be_dwbn, (float*)d_out);
}